// Round 1
// baseline (723.581 us; speedup 1.0000x reference)
//
#include <hip/hip_runtime.h>

typedef short s16x8 __attribute__((ext_vector_type(8)));
typedef unsigned short u16;
typedef u16 u16x8 __attribute__((ext_vector_type(8)));
typedef float f32x4 __attribute__((ext_vector_type(4)));

#define SEQ 4096
#define EMBED 1024
#define NQKV 3072

static __device__ __forceinline__ u16 f2bf(float f) {
  unsigned int u = __float_as_uint(f);
  u += 0x7fffu + ((u >> 16) & 1u);
  return (u16)(u >> 16);
}

static __device__ __forceinline__ f32x4 mfma16(s16x8 a, s16x8 b, f32x4 c) {
  return __builtin_amdgcn_mfma_f32_16x16x32_bf16(a, b, c, 0, 0, 0);
}

// ---------------- Kernel 1: QKV projection GEMM (fp32 in, bf16 out) --------
// C[4096][3072] = x[4096][1024] @ W[1024][3072] + b
// 128x128 tile, BK=32, 256 threads (4 waves, each wave a 64x64 quadrant).
__global__ __launch_bounds__(256) void qkv_gemm(const float* __restrict__ x,
                                                const float* __restrict__ W,
                                                const float* __restrict__ bias,
                                                u16* __restrict__ qkv) {
  __shared__ u16 xs[128][40];   // x tile  [m][k], +8 pad
  __shared__ u16 wsT[128][40];  // W tile transposed [n][k], +8 pad
  const int n0 = blockIdx.x * 128;
  const int m0 = blockIdx.y * 128;
  const int tid = threadIdx.x;
  const int w = tid >> 6, l = tid & 63;
  const int wr = (w >> 1) * 64, wc = (w & 1) * 64;
  const int lg = l >> 4, lr = l & 15;

  f32x4 acc[4][4];
#pragma unroll
  for (int i = 0; i < 4; ++i)
#pragma unroll
    for (int j = 0; j < 4; ++j) acc[i][j] = (f32x4){0.f, 0.f, 0.f, 0.f};

  const int xr = tid >> 3, xc = (tid & 7) * 4;   // x stage: 32 rows/pass
  const int wk = tid >> 5, wn = (tid & 31) * 4;  // W stage: 8 k-rows/pass

  for (int k0 = 0; k0 < EMBED; k0 += 32) {
    __syncthreads();
#pragma unroll
    for (int p = 0; p < 4; ++p) {
      int r = p * 32 + xr;
      float4 v = *reinterpret_cast<const float4*>(&x[(size_t)(m0 + r) * EMBED + k0 + xc]);
      xs[r][xc + 0] = f2bf(v.x); xs[r][xc + 1] = f2bf(v.y);
      xs[r][xc + 2] = f2bf(v.z); xs[r][xc + 3] = f2bf(v.w);
    }
#pragma unroll
    for (int p = 0; p < 4; ++p) {
      int k = p * 8 + wk;
      float4 v = *reinterpret_cast<const float4*>(&W[(size_t)(k0 + k) * NQKV + n0 + wn]);
      wsT[wn + 0][k] = f2bf(v.x); wsT[wn + 1][k] = f2bf(v.y);
      wsT[wn + 2][k] = f2bf(v.z); wsT[wn + 3][k] = f2bf(v.w);
    }
    __syncthreads();
    s16x8 af[4], bfr[4];
#pragma unroll
    for (int mb = 0; mb < 4; ++mb)
      af[mb] = *reinterpret_cast<const s16x8*>(&xs[wr + mb * 16 + lr][lg * 8]);
#pragma unroll
    for (int nb = 0; nb < 4; ++nb)
      bfr[nb] = *reinterpret_cast<const s16x8*>(&wsT[wc + nb * 16 + lr][lg * 8]);
#pragma unroll
    for (int mb = 0; mb < 4; ++mb)
#pragma unroll
      for (int nb = 0; nb < 4; ++nb)
        acc[mb][nb] = mfma16(af[mb], bfr[nb], acc[mb][nb]);
  }
#pragma unroll
  for (int mb = 0; mb < 4; ++mb)
#pragma unroll
    for (int nb = 0; nb < 4; ++nb) {
      const int col = n0 + wc + nb * 16 + lr;
      const float bv = bias[col];
#pragma unroll
      for (int e = 0; e < 4; ++e) {
        const int row = m0 + wr + mb * 16 + lg * 4 + e;
        qkv[(size_t)row * NQKV + col] = f2bf(acc[mb][nb][e] + bv);
      }
    }
}

// ---------------- Kernel 2: V transpose (bf16) ------------------------------
// vT[c][s] = qkv[s][2048 + c]   (so PV B-fragments get contiguous lane loads)
__global__ __launch_bounds__(256) void v_transpose(const u16* __restrict__ qkv,
                                                   u16* __restrict__ vT) {
  __shared__ u16 t[64][72];
  const int s0 = blockIdx.x * 64;
  const int c0 = blockIdx.y * 64;
  const int tid = threadIdx.x;
  const int rr = tid >> 3, c8 = (tid & 7) * 8;
#pragma unroll
  for (int p = 0; p < 2; ++p) {
    int r = p * 32 + rr;
    *reinterpret_cast<u16x8*>(&t[r][c8]) =
        *reinterpret_cast<const u16x8*>(&qkv[(size_t)(s0 + r) * NQKV + 2 * EMBED + c0 + c8]);
  }
  __syncthreads();
#pragma unroll
  for (int p = 0; p < 2; ++p) {
    int c = p * 32 + rr;
    u16x8 v;
#pragma unroll
    for (int j = 0; j < 8; ++j) v[j] = t[c8 + j][c];
    *reinterpret_cast<u16x8*>(&vT[(size_t)(c0 + c) * SEQ + s0 + c8]) = v;
  }
}

// ---------------- Kernel 3: causal flash attention --------------------------
// One block = one 16-row Q tile, 8 waves. KV tile = 128 keys.
// Wave w: QK for key-slice [16w,16w+16); PV for d-slice [128w,128w+128).
__global__ __launch_bounds__(512) void attn(const u16* __restrict__ qkv,
                                            const u16* __restrict__ vT,
                                            float* __restrict__ out) {
  __shared__ u16 q_lds[16][1032];
  __shared__ u16 p_lds[16][136];
  __shared__ float redmax[8][16];
  __shared__ float redsum[8][16];
  const int qb = blockIdx.x * 16;
  const int tid = threadIdx.x;
  const int w = tid >> 6, l = tid & 63;
  const int lg = l >> 4, lr = l & 15;

  // load Q tile (16 x 1024) into LDS, coalesced
#pragma unroll
  for (int p = 0; p < 4; ++p) {
    int idx = p * 512 + tid;
    int r = idx >> 7, c = (idx & 127) * 8;
    *reinterpret_cast<u16x8*>(&q_lds[r][c]) =
        *reinterpret_cast<const u16x8*>(&qkv[(size_t)(qb + r) * NQKV + c]);
  }
  __syncthreads();

  f32x4 o_acc[8];
#pragma unroll
  for (int nb = 0; nb < 8; ++nb) o_acc[nb] = (f32x4){0.f, 0.f, 0.f, 0.f};
  float m_st[4], l_st[4];
#pragma unroll
  for (int e = 0; e < 4; ++e) { m_st[e] = -__builtin_inff(); l_st[e] = 0.f; }

  const u16* kptr = qkv + EMBED;  // K starts at col 1024, row stride 3072
  const int ntiles = qb / 128 + 1;
  const int keyoff = w * 16 + lr;

  for (int t = 0; t < ntiles; ++t) {
    const int kb = t * 128;
    const int kcol = kb + keyoff;
    f32x4 s = (f32x4){0.f, 0.f, 0.f, 0.f};
    const u16* krow = kptr + (size_t)kcol * NQKV;
#pragma unroll
    for (int kk = 0; kk < 32; ++kk) {
      s16x8 a = *reinterpret_cast<const s16x8*>(&q_lds[lr][kk * 32 + lg * 8]);
      s16x8 b = *reinterpret_cast<const s16x8*>(&krow[kk * 32 + lg * 8]);
      s = mfma16(a, b, s);
    }
    // scale + causal mask; in-wave row max over the 16-lane group
    float sv[4], mx[4];
#pragma unroll
    for (int e = 0; e < 4; ++e) {
      float v = s[e] * 0.03125f;  // 1/sqrt(1024)
      sv[e] = (kcol > qb + lg * 4 + e) ? -__builtin_inff() : v;
      mx[e] = sv[e];
    }
#pragma unroll
    for (int off = 1; off < 16; off <<= 1)
#pragma unroll
      for (int e = 0; e < 4; ++e) mx[e] = fmaxf(mx[e], __shfl_xor(mx[e], off, 64));
    if (lr == 0) {
#pragma unroll
      for (int e = 0; e < 4; ++e) redmax[w][lg * 4 + e] = mx[e];
    }
    __syncthreads();  // B1

    float m_new[4], sc[4], pv[4], rs[4];
#pragma unroll
    for (int e = 0; e < 4; ++e) {
      float m = m_st[e];
#pragma unroll
      for (int ww = 0; ww < 8; ++ww) m = fmaxf(m, redmax[ww][lg * 4 + e]);
      m_new[e] = m;
      sc[e] = __expf(m_st[e] - m);
      pv[e] = __expf(sv[e] - m);
      rs[e] = pv[e];
    }
#pragma unroll
    for (int off = 1; off < 16; off <<= 1)
#pragma unroll
      for (int e = 0; e < 4; ++e) rs[e] += __shfl_xor(rs[e], off, 64);
    if (lr == 0) {
#pragma unroll
      for (int e = 0; e < 4; ++e) redsum[w][lg * 4 + e] = rs[e];
    }
#pragma unroll
    for (int e = 0; e < 4; ++e) p_lds[lg * 4 + e][w * 16 + lr] = f2bf(pv[e]);
    __syncthreads();  // B2

#pragma unroll
    for (int e = 0; e < 4; ++e) {
      float acc = l_st[e] * sc[e];
#pragma unroll
      for (int ww = 0; ww < 8; ++ww) acc += redsum[ww][lg * 4 + e];
      l_st[e] = acc;
      m_st[e] = m_new[e];
    }
#pragma unroll
    for (int nb = 0; nb < 8; ++nb)
#pragma unroll
      for (int e = 0; e < 4; ++e) o_acc[nb][e] *= sc[e];

    // PV: O[16 x 128-slice] += P(16x128) @ V(128 x 128-slice)
#pragma unroll
    for (int kk = 0; kk < 4; ++kk) {
      s16x8 a = *reinterpret_cast<const s16x8*>(&p_lds[lr][kk * 32 + lg * 8]);
#pragma unroll
      for (int nb = 0; nb < 8; ++nb) {
        s16x8 b = *reinterpret_cast<const s16x8*>(
            &vT[(size_t)(w * 128 + nb * 16 + lr) * SEQ + kb + kk * 32 + lg * 8]);
        o_acc[nb] = mfma16(a, b, o_acc[nb]);
      }
    }
  }

#pragma unroll
  for (int nb = 0; nb < 8; ++nb) {
    const int col = w * 128 + nb * 16 + lr;
#pragma unroll
    for (int e = 0; e < 4; ++e) {
      out[(size_t)(qb + lg * 4 + e) * EMBED + col] = o_acc[nb][e] / l_st[e];
    }
  }
}

extern "C" void kernel_launch(void* const* d_in, const int* in_sizes, int n_in,
                              void* d_out, int out_size, void* d_ws, size_t ws_size,
                              hipStream_t stream) {
  (void)in_sizes; (void)n_in; (void)out_size; (void)ws_size;
  const float* x = (const float*)d_in[0];
  const float* W = (const float*)d_in[1];
  const float* bias = (const float*)d_in[2];
  float* out = (float*)d_out;

  u16* qkv = (u16*)d_ws;                       // 4096*3072 bf16 = 24 MB
  u16* vT = qkv + (size_t)SEQ * NQKV;          // 1024*4096 bf16 =  8 MB

  dim3 g1(NQKV / 128, SEQ / 128);
  qkv_gemm<<<g1, 256, 0, stream>>>(x, W, bias, qkv);

  dim3 g2(SEQ / 64, EMBED / 64);
  v_transpose<<<g2, 256, 0, stream>>>(qkv, vT);

  attn<<<SEQ / 16, 512, 0, stream>>>(qkv, vT, out);
}

// Round 3
// 373.538 us; speedup vs baseline: 1.9371x; 1.9371x over previous
//
#include <hip/hip_runtime.h>

typedef short s16x8 __attribute__((ext_vector_type(8)));
typedef unsigned short u16;
typedef u16 u16x8 __attribute__((ext_vector_type(8)));
typedef float f32x4 __attribute__((ext_vector_type(4)));

#define SEQ 4096
#define EMBED 1024
#define NQKV 3072

static __device__ __forceinline__ u16 f2bf(float f) {
  unsigned int u = __float_as_uint(f);
  u += 0x7fffu + ((u >> 16) & 1u);
  return (u16)(u >> 16);
}

static __device__ __forceinline__ f32x4 mfma16(s16x8 a, s16x8 b, f32x4 c) {
  return __builtin_amdgcn_mfma_f32_16x16x32_bf16(a, b, c, 0, 0, 0);
}

static __device__ __forceinline__ void gl2lds(const u16* g, u16* l) {
  __builtin_amdgcn_global_load_lds(
      (const __attribute__((address_space(1))) unsigned int*)g,
      (__attribute__((address_space(3))) unsigned int*)l, 16, 0, 0);
}

#define WAITVM(n) asm volatile("s_waitcnt vmcnt(" #n ")" ::: "memory")
#define LGKM0 asm volatile("s_waitcnt lgkmcnt(0)" ::: "memory")
#define BAR() asm volatile("s_waitcnt lgkmcnt(0)\n\ts_barrier" ::: "memory")

// ---------------- Kernel 1: QKV projection GEMM (fp32 in, bf16 out) --------
__global__ __launch_bounds__(256) void qkv_gemm(const float* __restrict__ x,
                                                const float* __restrict__ W,
                                                const float* __restrict__ bias,
                                                u16* __restrict__ qkv) {
  __shared__ u16 xs[128][40];
  __shared__ u16 wsT[128][40];
  const int n0 = blockIdx.x * 128;
  const int m0 = blockIdx.y * 128;
  const int tid = threadIdx.x;
  const int w = tid >> 6, l = tid & 63;
  const int wr = (w >> 1) * 64, wc = (w & 1) * 64;
  const int lg = l >> 4, lr = l & 15;

  f32x4 acc[4][4];
#pragma unroll
  for (int i = 0; i < 4; ++i)
#pragma unroll
    for (int j = 0; j < 4; ++j) acc[i][j] = (f32x4){0.f, 0.f, 0.f, 0.f};

  const int xr = tid >> 3, xc = (tid & 7) * 4;
  const int wk = tid >> 5, wn = (tid & 31) * 4;

  for (int k0 = 0; k0 < EMBED; k0 += 32) {
    __syncthreads();
#pragma unroll
    for (int p = 0; p < 4; ++p) {
      int r = p * 32 + xr;
      float4 v = *reinterpret_cast<const float4*>(&x[(size_t)(m0 + r) * EMBED + k0 + xc]);
      xs[r][xc + 0] = f2bf(v.x); xs[r][xc + 1] = f2bf(v.y);
      xs[r][xc + 2] = f2bf(v.z); xs[r][xc + 3] = f2bf(v.w);
    }
#pragma unroll
    for (int p = 0; p < 4; ++p) {
      int k = p * 8 + wk;
      float4 v = *reinterpret_cast<const float4*>(&W[(size_t)(k0 + k) * NQKV + n0 + wn]);
      wsT[wn + 0][k] = f2bf(v.x); wsT[wn + 1][k] = f2bf(v.y);
      wsT[wn + 2][k] = f2bf(v.z); wsT[wn + 3][k] = f2bf(v.w);
    }
    __syncthreads();
    s16x8 af[4], bfr[4];
#pragma unroll
    for (int mb = 0; mb < 4; ++mb)
      af[mb] = *reinterpret_cast<const s16x8*>(&xs[wr + mb * 16 + lr][lg * 8]);
#pragma unroll
    for (int nb = 0; nb < 4; ++nb)
      bfr[nb] = *reinterpret_cast<const s16x8*>(&wsT[wc + nb * 16 + lr][lg * 8]);
#pragma unroll
    for (int mb = 0; mb < 4; ++mb)
#pragma unroll
      for (int nb = 0; nb < 4; ++nb)
        acc[mb][nb] = mfma16(af[mb], bfr[nb], acc[mb][nb]);
  }
#pragma unroll
  for (int mb = 0; mb < 4; ++mb)
#pragma unroll
    for (int nb = 0; nb < 4; ++nb) {
      const int col = n0 + wc + nb * 16 + lr;
      const float bv = bias[col];
#pragma unroll
      for (int e = 0; e < 4; ++e) {
        const int row = m0 + wr + mb * 16 + lg * 4 + e;
        qkv[(size_t)row * NQKV + col] = f2bf(acc[mb][nb][e] + bv);
      }
    }
}

// ---------------- Kernel 2: V transpose (bf16) ------------------------------
__global__ __launch_bounds__(256) void v_transpose(const u16* __restrict__ qkv,
                                                   u16* __restrict__ vT) {
  __shared__ u16 t[64][72];
  const int s0 = blockIdx.x * 64;
  const int c0 = blockIdx.y * 64;
  const int tid = threadIdx.x;
  const int rr = tid >> 3, c8 = (tid & 7) * 8;
#pragma unroll
  for (int p = 0; p < 2; ++p) {
    int r = p * 32 + rr;
    *reinterpret_cast<u16x8*>(&t[r][c8]) =
        *reinterpret_cast<const u16x8*>(&qkv[(size_t)(s0 + r) * NQKV + 2 * EMBED + c0 + c8]);
  }
  __syncthreads();
#pragma unroll
  for (int p = 0; p < 2; ++p) {
    int c = p * 32 + rr;
    u16x8 v;
#pragma unroll
    for (int j = 0; j < 8; ++j) v[j] = t[c8 + j][c];
    *reinterpret_cast<u16x8*>(&vT[(size_t)(c0 + c) * SEQ + s0 + c8]) = v;
  }
}

// ---------------- Kernel 3: causal flash attention --------------------------
// Block = 16 Q-rows, 8 waves, KV tile = 128 keys.
// QK: wave w owns keys [16w,16w+16). PV: wave w owns d-cols {j*128+16w+lr}.
// K/V staged per-wave into private LDS chunks via global_load_lds with
// source-side XOR swizzle; double-buffered with counted vmcnt. Q in VGPRs.
// LGKM0 before every STAGE: WAR fence — prior ds_reads of the buffer being
// restaged must retire before the DMA write can land (R2's race).
__global__ __launch_bounds__(512) void attn(const u16* __restrict__ qkv,
                                            const u16* __restrict__ vT,
                                            float* __restrict__ out) {
  __shared__ u16 q_lds[16][1032];       // 33.0 KB (staging only)
  __shared__ u16 kv_lds[8][2][2048];    // 64 KB: per-wave dbuf chunk [16][128]
  __shared__ u16 p_lds[16][136];        // 4.25 KB
  __shared__ float redmax[8][16];
  __shared__ float redsum[8][16];
  const int qb = blockIdx.x * 16;
  const int tid = threadIdx.x;
  const int w = tid >> 6, l = tid & 63;
  const int lg = l >> 4, lr = l & 15;

  // ---- load Q tile (16 x 1024) coalesced into LDS, then into registers ----
#pragma unroll
  for (int p = 0; p < 4; ++p) {
    int idx = p * 512 + tid;
    int r = idx >> 7, c = (idx & 127) * 8;
    *reinterpret_cast<u16x8*>(&q_lds[r][c]) =
        *reinterpret_cast<const u16x8*>(&qkv[(size_t)(qb + r) * NQKV + c]);
  }
  __syncthreads();
  s16x8 qf[32];
#pragma unroll
  for (int kk = 0; kk < 32; ++kk)
    qf[kk] = *reinterpret_cast<const s16x8*>(&q_lds[lr][kk * 32 + lg * 8]);

  // ---- per-lane constants ----
  const int sr = l >> 4;                 // staging row-in-group 0..3
  const int scb = (l & 15) * 16;         // staging byte col 0..240
  const int scolA = ((scb ^ (sr << 4)) >> 1);        // rows with (r&7)==sr
  const int scolB = ((scb ^ ((4 + sr) << 4)) >> 1);  // rows with (r&7)==4+sr
  int boff[4];
#pragma unroll
  for (int kk = 0; kk < 4; ++kk)
    boff[kk] = lr * 256 + ((kk * 64 + lg * 16) ^ ((lr & 7) << 4));

  u16* kvb0 = &kv_lds[w][0][0];
  u16* kvb1 = &kv_lds[w][1][0];

#define STAGE_K(dc, bufp)                                                     \
  {                                                                           \
    LGKM0;                                                                    \
    const u16* g0 = qkv + (size_t)(kb + w * 16 + sr) * NQKV + EMBED + (dc) * 128; \
    gl2lds(g0 + scolA, (bufp));                                               \
    gl2lds(g0 + 4 * NQKV + scolB, (bufp) + 512);                              \
    gl2lds(g0 + 8 * NQKV + scolA, (bufp) + 1024);                             \
    gl2lds(g0 + 12 * NQKV + scolB, (bufp) + 1536);                            \
  }
#define STAGE_V(j, bufp)                                                      \
  {                                                                           \
    LGKM0;                                                                    \
    const u16* g0 = vT + (size_t)((j) * 128 + w * 16 + sr) * SEQ + kb;        \
    gl2lds(g0 + scolA, (bufp));                                               \
    gl2lds(g0 + 4 * SEQ + scolB, (bufp) + 512);                               \
    gl2lds(g0 + 8 * SEQ + scolA, (bufp) + 1024);                              \
    gl2lds(g0 + 12 * SEQ + scolB, (bufp) + 1536);                             \
  }

  f32x4 o_acc[8];
#pragma unroll
  for (int j = 0; j < 8; ++j) o_acc[j] = (f32x4){0.f, 0.f, 0.f, 0.f};
  float m_st[4], l_st[4];
#pragma unroll
  for (int e = 0; e < 4; ++e) { m_st[e] = -__builtin_inff(); l_st[e] = 0.f; }

  const int ntiles = qb / 128 + 1;

  for (int t = 0; t < ntiles; ++t) {
    const int kb = t * 128;
    const int kcol = kb + w * 16 + lr;

    // ---- QK^T: 8 d-chunks of [16 keys][128 d], double-buffered ----
    f32x4 s = (f32x4){0.f, 0.f, 0.f, 0.f};
    STAGE_K(0, kvb0);
#pragma unroll
    for (int dc = 0; dc < 8; ++dc) {
      u16* cur = (dc & 1) ? kvb1 : kvb0;
      if (dc < 7) {
        u16* nxt = (dc & 1) ? kvb0 : kvb1;
        STAGE_K(dc + 1, nxt);
        WAITVM(4);
      } else {
        WAITVM(0);
      }
#pragma unroll
      for (int kk = 0; kk < 4; ++kk) {
        s16x8 b = *reinterpret_cast<const s16x8*>((const char*)cur + boff[kk]);
        s = mfma16(qf[dc * 4 + kk], b, s);
      }
    }

    // prefetch first V chunk; latency hides under softmax + barriers
    STAGE_V(0, kvb0);

    // ---- softmax (scale, mask, online m/l across 8 waves) ----
    float sv[4], mx[4];
#pragma unroll
    for (int e = 0; e < 4; ++e) {
      float v = s[e] * 0.03125f;  // 1/sqrt(1024)
      sv[e] = (kcol > qb + lg * 4 + e) ? -__builtin_inff() : v;
      mx[e] = sv[e];
    }
#pragma unroll
    for (int off = 1; off < 16; off <<= 1)
#pragma unroll
      for (int e = 0; e < 4; ++e) mx[e] = fmaxf(mx[e], __shfl_xor(mx[e], off, 64));
    if (lr == 0) {
#pragma unroll
      for (int e = 0; e < 4; ++e) redmax[w][lg * 4 + e] = mx[e];
    }
    BAR();  // B1

    float m_new[4], sc[4], pv[4], rs[4];
#pragma unroll
    for (int e = 0; e < 4; ++e) {
      float m = m_st[e];
#pragma unroll
      for (int ww = 0; ww < 8; ++ww) m = fmaxf(m, redmax[ww][lg * 4 + e]);
      m_new[e] = m;
      sc[e] = __expf(m_st[e] - m);
      pv[e] = __expf(sv[e] - m);
      rs[e] = pv[e];
    }
#pragma unroll
    for (int off = 1; off < 16; off <<= 1)
#pragma unroll
      for (int e = 0; e < 4; ++e) rs[e] += __shfl_xor(rs[e], off, 64);
    if (lr == 0) {
#pragma unroll
      for (int e = 0; e < 4; ++e) redsum[w][lg * 4 + e] = rs[e];
    }
#pragma unroll
    for (int e = 0; e < 4; ++e) p_lds[lg * 4 + e][w * 16 + lr] = f2bf(pv[e]);
    BAR();  // B2

#pragma unroll
    for (int e = 0; e < 4; ++e) {
      float acc = l_st[e] * sc[e];
#pragma unroll
      for (int ww = 0; ww < 8; ++ww) acc += redsum[ww][lg * 4 + e];
      l_st[e] = acc;
      m_st[e] = m_new[e];
    }
#pragma unroll
    for (int j = 0; j < 8; ++j)
#pragma unroll
      for (int e = 0; e < 4; ++e) o_acc[j][e] *= sc[e];

    s16x8 pa[4];
#pragma unroll
    for (int kk = 0; kk < 4; ++kk)
      pa[kk] = *reinterpret_cast<const s16x8*>(&p_lds[lr][kk * 32 + lg * 8]);

    // ---- PV: 8 d-chunks of [16 d][128 keys], double-buffered ----
#pragma unroll
    for (int j = 0; j < 8; ++j) {
      u16* cur = (j & 1) ? kvb1 : kvb0;
      if (j < 7) {
        u16* nxt = (j & 1) ? kvb0 : kvb1;
        STAGE_V(j + 1, nxt);
        WAITVM(4);
      } else {
        WAITVM(0);
      }
#pragma unroll
      for (int kk = 0; kk < 4; ++kk) {
        s16x8 b = *reinterpret_cast<const s16x8*>((const char*)cur + boff[kk]);
        o_acc[j] = mfma16(pa[kk], b, o_acc[j]);
      }
    }
  }

  // ---- epilogue ----
#pragma unroll
  for (int j = 0; j < 8; ++j) {
    const int col = j * 128 + w * 16 + lr;
#pragma unroll
    for (int e = 0; e < 4; ++e) {
      out[(size_t)(qb + lg * 4 + e) * EMBED + col] = o_acc[j][e] / l_st[e];
    }
  }
}

extern "C" void kernel_launch(void* const* d_in, const int* in_sizes, int n_in,
                              void* d_out, int out_size, void* d_ws, size_t ws_size,
                              hipStream_t stream) {
  (void)in_sizes; (void)n_in; (void)out_size; (void)ws_size;
  const float* x = (const float*)d_in[0];
  const float* W = (const float*)d_in[1];
  const float* bias = (const float*)d_in[2];
  float* out = (float*)d_out;

  u16* qkv = (u16*)d_ws;                 // 4096*3072 bf16 = 24 MB
  u16* vT = qkv + (size_t)SEQ * NQKV;    // 1024*4096 bf16 =  8 MB

  dim3 g1(NQKV / 128, SEQ / 128);
  qkv_gemm<<<g1, 256, 0, stream>>>(x, W, bias, qkv);

  dim3 g2(SEQ / 64, EMBED / 64);
  v_transpose<<<g2, 256, 0, stream>>>(qkv, vT);

  attn<<<SEQ / 16, 512, 0, stream>>>(qkv, vT, out);
}

// Round 4
// 239.645 us; speedup vs baseline: 3.0194x; 1.5587x over previous
//
#include <hip/hip_runtime.h>

typedef short s16x8 __attribute__((ext_vector_type(8)));
typedef unsigned short u16;
typedef u16 u16x8 __attribute__((ext_vector_type(8)));
typedef float f32x4 __attribute__((ext_vector_type(4)));

#define SEQ 4096
#define EMBED 1024
#define NQKV 3072

static __device__ __forceinline__ u16 f2bf(float f) {
  unsigned int u = __float_as_uint(f);
  u += 0x7fffu + ((u >> 16) & 1u);
  return (u16)(u >> 16);
}

static __device__ __forceinline__ f32x4 mfma16(s16x8 a, s16x8 b, f32x4 c) {
  return __builtin_amdgcn_mfma_f32_16x16x32_bf16(a, b, c, 0, 0, 0);
}

static __device__ __forceinline__ void gl2lds(const u16* g, u16* l) {
  __builtin_amdgcn_global_load_lds(
      (const __attribute__((address_space(1))) unsigned int*)g,
      (__attribute__((address_space(3))) unsigned int*)l, 16, 0, 0);
}

#define WAITVM(n) asm volatile("s_waitcnt vmcnt(" #n ")" ::: "memory")
#define LGKM0 asm volatile("s_waitcnt lgkmcnt(0)" ::: "memory")
#define BAR() asm volatile("s_waitcnt lgkmcnt(0)\n\ts_barrier" ::: "memory")

// ---------------- Kernel 0a: x f32 -> bf16 ----------------------------------
__global__ __launch_bounds__(256) void conv_x(const float* __restrict__ x,
                                              u16* __restrict__ xbf) {
  const size_t base = ((size_t)blockIdx.x * 256 + threadIdx.x) * 16;
  u16 tmp[16];
#pragma unroll
  for (int p = 0; p < 4; ++p) {
    float4 v = *reinterpret_cast<const float4*>(&x[base + p * 4]);
    tmp[p * 4 + 0] = f2bf(v.x); tmp[p * 4 + 1] = f2bf(v.y);
    tmp[p * 4 + 2] = f2bf(v.z); tmp[p * 4 + 3] = f2bf(v.w);
  }
  *reinterpret_cast<u16x8*>(&xbf[base]) = *reinterpret_cast<u16x8*>(&tmp[0]);
  *reinterpret_cast<u16x8*>(&xbf[base + 8]) = *reinterpret_cast<u16x8*>(&tmp[8]);
}

// ---------------- Kernel 0b: W[k][n] f32 -> WT[n][k] bf16 --------------------
__global__ __launch_bounds__(256) void conv_wT(const float* __restrict__ W,
                                               u16* __restrict__ wT) {
  __shared__ u16 t[64][72];
  const int n0 = blockIdx.x * 64;
  const int k0 = blockIdx.y * 64;
  const int tid = threadIdx.x;
  const int rr = tid >> 3, c8 = (tid & 7) * 8;
#pragma unroll
  for (int p = 0; p < 2; ++p) {
    int r = p * 32 + rr;
    float4 a = *reinterpret_cast<const float4*>(&W[(size_t)(k0 + r) * NQKV + n0 + c8]);
    float4 b = *reinterpret_cast<const float4*>(&W[(size_t)(k0 + r) * NQKV + n0 + c8 + 4]);
    t[r][c8 + 0] = f2bf(a.x); t[r][c8 + 1] = f2bf(a.y);
    t[r][c8 + 2] = f2bf(a.z); t[r][c8 + 3] = f2bf(a.w);
    t[r][c8 + 4] = f2bf(b.x); t[r][c8 + 5] = f2bf(b.y);
    t[r][c8 + 6] = f2bf(b.z); t[r][c8 + 7] = f2bf(b.w);
  }
  __syncthreads();
#pragma unroll
  for (int p = 0; p < 2; ++p) {
    int c = p * 32 + rr;  // n-index within tile
    u16x8 v;
#pragma unroll
    for (int j = 0; j < 8; ++j) v[j] = t[c8 + j][c];
    *reinterpret_cast<u16x8*>(&wT[(size_t)(n0 + c) * EMBED + k0 + c8]) = v;
  }
}

// ---------------- Kernel 1: QKV GEMM, bf16 in/out, m97-style -----------------
// C[4096][3072] = xbf[4096][1024] @ WT[3072][1024]^T + b; 128x128 tile, BK=64.
__global__ __launch_bounds__(256) void qkv_gemm(const u16* __restrict__ xbf,
                                                const u16* __restrict__ wT,
                                                const float* __restrict__ bias,
                                                u16* __restrict__ qkv) {
  __shared__ u16 As[2][8192];  // [128 m][64 k], XOR-swizzled 16B slots
  __shared__ u16 Bs[2][8192];  // [128 n][64 k]
  const int b = blockIdx.x;
  const int bs = (b & 7) * 96 + (b >> 3);   // XCD swizzle (768 % 8 == 0)
  const int bm = bs / 24, bn = bs % 24;
  const int m0 = bm * 128, n0 = bn * 128;
  const int tid = threadIdx.x;
  const int w = tid >> 6, l = tid & 63;
  const int wr = (w >> 1) * 64, wc = (w & 1) * 64;
  const int lg = l >> 4, lr = l & 15;

  // per-lane staging constants: lane covers row (l>>3), 16B slot (l&7),
  // source column pre-swizzled by row&7 (dest linear).
  const int srow = l >> 3;
  const int scol = ((l & 7) ^ (srow & 7)) << 3;  // elem offset in row

#define GSTAGE(dst, srcbase)                                                  \
  {                                                                           \
    _Pragma("unroll") for (int c = 0; c < 4; ++c) {                           \
      gl2lds((srcbase) + (size_t)((c * 4 + w) * 8 + srow) * EMBED + scol,     \
             (dst) + (c * 4 + w) * 512);                                      \
    }                                                                         \
  }

  f32x4 acc[4][4];
#pragma unroll
  for (int i = 0; i < 4; ++i)
#pragma unroll
    for (int j = 0; j < 4; ++j) acc[i][j] = (f32x4){0.f, 0.f, 0.f, 0.f};

  const u16* xa = xbf + (size_t)m0 * EMBED;
  const u16* wb = wT + (size_t)n0 * EMBED;

  GSTAGE(As[0], xa);
  GSTAGE(Bs[0], wb);

  for (int t = 0; t < 16; ++t) {
    const int cur = t & 1, nx = cur ^ 1;
    if (t < 15) {
      LGKM0;
      GSTAGE(As[nx], xa + (t + 1) * 64);
      GSTAGE(Bs[nx], wb + (t + 1) * 64);
      WAITVM(8);
    } else {
      WAITVM(0);
    }
    BAR();
#pragma unroll
    for (int kk = 0; kk < 2; ++kk) {
      const int csw = (kk * 32 + lg * 8) ^ ((lr & 7) << 3);
      s16x8 af[4], bfr[4];
#pragma unroll
      for (int mb = 0; mb < 4; ++mb)
        af[mb] = *reinterpret_cast<const s16x8*>(&As[cur][(wr + mb * 16 + lr) * 64 + csw]);
#pragma unroll
      for (int nb = 0; nb < 4; ++nb)
        bfr[nb] = *reinterpret_cast<const s16x8*>(&Bs[cur][(wc + nb * 16 + lr) * 64 + csw]);
#pragma unroll
      for (int mb = 0; mb < 4; ++mb)
#pragma unroll
        for (int nb = 0; nb < 4; ++nb)
          acc[mb][nb] = mfma16(af[mb], bfr[nb], acc[mb][nb]);
    }
    BAR();
  }

#pragma unroll
  for (int mb = 0; mb < 4; ++mb)
#pragma unroll
    for (int nb = 0; nb < 4; ++nb) {
      const int col = n0 + wc + nb * 16 + lr;
      const float bv = bias[col];
#pragma unroll
      for (int e = 0; e < 4; ++e) {
        const int row = m0 + wr + mb * 16 + lg * 4 + e;
        qkv[(size_t)row * NQKV + col] = f2bf(acc[mb][nb][e] + bv);
      }
    }
#undef GSTAGE
}

// ---------------- Kernel 2: V transpose (bf16) ------------------------------
__global__ __launch_bounds__(256) void v_transpose(const u16* __restrict__ qkv,
                                                   u16* __restrict__ vT) {
  __shared__ u16 t[64][72];
  const int s0 = blockIdx.x * 64;
  const int c0 = blockIdx.y * 64;
  const int tid = threadIdx.x;
  const int rr = tid >> 3, c8 = (tid & 7) * 8;
#pragma unroll
  for (int p = 0; p < 2; ++p) {
    int r = p * 32 + rr;
    *reinterpret_cast<u16x8*>(&t[r][c8]) =
        *reinterpret_cast<const u16x8*>(&qkv[(size_t)(s0 + r) * NQKV + 2 * EMBED + c0 + c8]);
  }
  __syncthreads();
#pragma unroll
  for (int p = 0; p < 2; ++p) {
    int c = p * 32 + rr;
    u16x8 v;
#pragma unroll
    for (int j = 0; j < 8; ++j) v[j] = t[c8 + j][c];
    *reinterpret_cast<u16x8*>(&vT[(size_t)(c0 + c) * SEQ + s0 + c8]) = v;
  }
}

// ---------------- Kernel 3: causal flash attention --------------------------
// Block = 16 Q-rows/job, 8 waves, KV tile = 128 keys, 3-deep per-wave pipeline.
// mode 0: block bid handles q-tile bid fully, normalized write to out.
// mode 1 (balanced split): job0 = q-tile bid, even key-tiles -> numerator to
// out + ml side 0; job1 = q-tile 255-bid, odd key-tiles -> part + ml side 1.
__global__ __launch_bounds__(512) void attn(const u16* __restrict__ qkv,
                                            const u16* __restrict__ vT,
                                            float* __restrict__ out,
                                            float* __restrict__ part,
                                            float* __restrict__ ml,
                                            int mode) {
  __shared__ u16 q_lds[16][1032];
  __shared__ u16 kv_lds[8][3][2048];   // 96 KB: per-wave 3-buffered [16][128]
  __shared__ u16 p_lds[16][136];
  __shared__ float redmax[8][16];
  __shared__ float redsum[8][16];
  const int bid = blockIdx.x;
  const int tid = threadIdx.x;
  const int w = tid >> 6, l = tid & 63;
  const int lg = l >> 4, lr = l & 15;

  const int sr = l >> 4;
  const int scb = (l & 15) * 16;
  const int scolA = ((scb ^ (sr << 4)) >> 1);
  const int scolB = ((scb ^ ((4 + sr) << 4)) >> 1);
  int boff[4];
#pragma unroll
  for (int kk = 0; kk < 4; ++kk)
    boff[kk] = lr * 256 + ((kk * 64 + lg * 16) ^ ((lr & 7) << 4));

  u16* kvb[3] = {&kv_lds[w][0][0], &kv_lds[w][1][0], &kv_lds[w][2][0]};

#define STAGE_K(dc, bufp)                                                     \
  {                                                                           \
    LGKM0;                                                                    \
    const u16* g0 = qkv + (size_t)(kb + w * 16 + sr) * NQKV + EMBED + (dc) * 128; \
    gl2lds(g0 + scolA, (bufp));                                               \
    gl2lds(g0 + 4 * NQKV + scolB, (bufp) + 512);                              \
    gl2lds(g0 + 8 * NQKV + scolA, (bufp) + 1024);                             \
    gl2lds(g0 + 12 * NQKV + scolB, (bufp) + 1536);                            \
  }
#define STAGE_V(j, bufp)                                                      \
  {                                                                           \
    LGKM0;                                                                    \
    const u16* g0 = vT + (size_t)((j) * 128 + w * 16 + sr) * SEQ + kb;        \
    gl2lds(g0 + scolA, (bufp));                                               \
    gl2lds(g0 + 4 * SEQ + scolB, (bufp) + 512);                               \
    gl2lds(g0 + 8 * SEQ + scolA, (bufp) + 1024);                              \
    gl2lds(g0 + 12 * SEQ + scolB, (bufp) + 1536);                             \
  }

  const int njobs = mode ? 2 : 1;
  for (int job = 0; job < njobs; ++job) {
    const int qt = job ? (255 - bid) : bid;
    const int qb = qt * 16;
    const int nkt = qt / 8 + 1;
    const int kt0 = mode ? job : 0;
    const int ktstep = mode ? 2 : 1;
    const int n_it = mode ? (job ? (nkt >> 1) : ((nkt + 1) >> 1)) : nkt;

    // ---- load Q tile into LDS, then registers ----
    __syncthreads();
#pragma unroll
    for (int p = 0; p < 4; ++p) {
      int idx = p * 512 + tid;
      int r = idx >> 7, c = (idx & 127) * 8;
      *reinterpret_cast<u16x8*>(&q_lds[r][c]) =
          *reinterpret_cast<const u16x8*>(&qkv[(size_t)(qb + r) * NQKV + c]);
    }
    __syncthreads();
    s16x8 qf[32];
#pragma unroll
    for (int kk = 0; kk < 32; ++kk)
      qf[kk] = *reinterpret_cast<const s16x8*>(&q_lds[lr][kk * 32 + lg * 8]);

    f32x4 o_acc[8];
#pragma unroll
    for (int j = 0; j < 8; ++j) o_acc[j] = (f32x4){0.f, 0.f, 0.f, 0.f};
    float m_st[4], l_st[4];
#pragma unroll
    for (int e = 0; e < 4; ++e) { m_st[e] = -__builtin_inff(); l_st[e] = 0.f; }

    for (int it = 0; it < n_it; ++it) {
      const int kb = (kt0 + it * ktstep) * 128;
      const int kcol = kb + w * 16 + lr;

      // ---- QK^T: 8 d-chunks, 3-deep pipeline; V0/V1 prefetch at dc=6,7 ----
      f32x4 s = (f32x4){0.f, 0.f, 0.f, 0.f};
      STAGE_K(0, kvb[0]);
      STAGE_K(1, kvb[1]);
#pragma unroll
      for (int dc = 0; dc < 8; ++dc) {
        if (dc < 6) {
          STAGE_K(dc + 2, kvb[(dc + 2) % 3]);
        } else if (dc == 6) {
          STAGE_V(0, kvb[2]);
        } else {
          STAGE_V(1, kvb[0]);
        }
        WAITVM(8);
        u16* cur = kvb[dc % 3];
#pragma unroll
        for (int kk = 0; kk < 4; ++kk) {
          s16x8 bfr = *reinterpret_cast<const s16x8*>((const char*)cur + boff[kk]);
          s = mfma16(qf[dc * 4 + kk], bfr, s);
        }
      }

      // ---- softmax (scale, mask, online m/l across 8 waves) ----
      float sv[4], mx[4];
#pragma unroll
      for (int e = 0; e < 4; ++e) {
        float v = s[e] * 0.03125f;  // 1/sqrt(1024)
        sv[e] = (kcol > qb + lg * 4 + e) ? -__builtin_inff() : v;
        mx[e] = sv[e];
      }
#pragma unroll
      for (int off = 1; off < 16; off <<= 1)
#pragma unroll
        for (int e = 0; e < 4; ++e) mx[e] = fmaxf(mx[e], __shfl_xor(mx[e], off, 64));
      if (lr == 0) {
#pragma unroll
        for (int e = 0; e < 4; ++e) redmax[w][lg * 4 + e] = mx[e];
      }
      BAR();  // B1

      float m_new[4], sc[4], pv[4], rs[4];
#pragma unroll
      for (int e = 0; e < 4; ++e) {
        float m = m_st[e];
#pragma unroll
        for (int ww = 0; ww < 8; ++ww) m = fmaxf(m, redmax[ww][lg * 4 + e]);
        m_new[e] = m;
        sc[e] = __expf(m_st[e] - m);
        pv[e] = __expf(sv[e] - m);
        rs[e] = pv[e];
      }
#pragma unroll
      for (int off = 1; off < 16; off <<= 1)
#pragma unroll
        for (int e = 0; e < 4; ++e) rs[e] += __shfl_xor(rs[e], off, 64);
      if (lr == 0) {
#pragma unroll
        for (int e = 0; e < 4; ++e) redsum[w][lg * 4 + e] = rs[e];
      }
#pragma unroll
      for (int e = 0; e < 4; ++e) p_lds[lg * 4 + e][w * 16 + lr] = f2bf(pv[e]);
      BAR();  // B2

#pragma unroll
      for (int e = 0; e < 4; ++e) {
        float acc = l_st[e] * sc[e];
#pragma unroll
        for (int ww = 0; ww < 8; ++ww) acc += redsum[ww][lg * 4 + e];
        l_st[e] = acc;
        m_st[e] = m_new[e];
      }
#pragma unroll
      for (int j = 0; j < 8; ++j)
#pragma unroll
        for (int e = 0; e < 4; ++e) o_acc[j][e] *= sc[e];

      s16x8 pa[4];
#pragma unroll
      for (int kk = 0; kk < 4; ++kk)
        pa[kk] = *reinterpret_cast<const s16x8*>(&p_lds[lr][kk * 32 + lg * 8]);

      // ---- PV: 8 d-chunks, 3-deep pipeline (Vj in kvb[(j+2)%3]) ----
#pragma unroll
      for (int j = 0; j < 8; ++j) {
        if (j < 6) {
          STAGE_V(j + 2, kvb[(j + 4) % 3]);
          WAITVM(8);
        } else if (j == 6) {
          WAITVM(4);
        } else {
          WAITVM(0);
        }
        u16* cur = kvb[(j + 2) % 3];
#pragma unroll
        for (int kk = 0; kk < 4; ++kk) {
          s16x8 bfr = *reinterpret_cast<const s16x8*>((const char*)cur + boff[kk]);
          o_acc[j] = mfma16(pa[kk], bfr, o_acc[j]);
        }
      }
    }

    // ---- epilogue ----
    if (mode == 0) {
#pragma unroll
      for (int j = 0; j < 8; ++j) {
        const int col = j * 128 + w * 16 + lr;
#pragma unroll
        for (int e = 0; e < 4; ++e)
          out[(size_t)(qb + lg * 4 + e) * EMBED + col] = o_acc[j][e] / l_st[e];
      }
    } else {
      float* dst = job ? part : out;
#pragma unroll
      for (int j = 0; j < 8; ++j) {
        const int col = j * 128 + w * 16 + lr;
#pragma unroll
        for (int e = 0; e < 4; ++e)
          dst[(size_t)(qb + lg * 4 + e) * EMBED + col] = o_acc[j][e];
      }
      if (w == 0 && lr == 0) {
#pragma unroll
        for (int e = 0; e < 4; ++e) {
          ml[qt * 64 + job * 32 + (lg * 4 + e) * 2] = m_st[e];
          ml[qt * 64 + job * 32 + (lg * 4 + e) * 2 + 1] = l_st[e];
        }
      }
    }
  }
#undef STAGE_K
#undef STAGE_V
}

// ---------------- Kernel 4: merge the two partials per q-tile ----------------
__global__ __launch_bounds__(256) void attn_merge(const float* __restrict__ ml,
                                                  const float* __restrict__ part,
                                                  float* __restrict__ out) {
  const int qt = blockIdx.x;
  const int r = threadIdx.x >> 4;
  const int c0 = (threadIdx.x & 15) * 64;
  const float mA = ml[qt * 64 + r * 2], lA = ml[qt * 64 + r * 2 + 1];
  const float mB = ml[qt * 64 + 32 + r * 2], lB = ml[qt * 64 + 32 + r * 2 + 1];
  const float m = fmaxf(mA, mB);
  const float wA = __expf(mA - m);
  const float wB = (lB > 0.f) ? __expf(mB - m) : 0.f;
  const float inv = 1.f / (lA * wA + lB * wB);
  const size_t base = (size_t)(qt * 16 + r) * EMBED + c0;
#pragma unroll
  for (int i = 0; i < 16; ++i) {
    float4 a = *reinterpret_cast<const float4*>(&out[base + i * 4]);
    float4 bq = *reinterpret_cast<const float4*>(&part[base + i * 4]);
    float4 o;
    o.x = (a.x * wA + bq.x * wB) * inv;
    o.y = (a.y * wA + bq.y * wB) * inv;
    o.z = (a.z * wA + bq.z * wB) * inv;
    o.w = (a.w * wA + bq.w * wB) * inv;
    *reinterpret_cast<float4*>(&out[base + i * 4]) = o;
  }
}

extern "C" void kernel_launch(void* const* d_in, const int* in_sizes, int n_in,
                              void* d_out, int out_size, void* d_ws, size_t ws_size,
                              hipStream_t stream) {
  (void)in_sizes; (void)n_in; (void)out_size;
  const float* x = (const float*)d_in[0];
  const float* W = (const float*)d_in[1];
  const float* bias = (const float*)d_in[2];
  float* out = (float*)d_out;

  u16* qkv = (u16*)d_ws;                               // [0,24) MB
  u16* vT = qkv + (size_t)SEQ * NQKV;                  // [24,32) MB
  u16* xbf = vT;                                       // xbf aliases vT region (dead before v_transpose)
  u16* wT = (u16*)d_out;                               // 6 MB scratch in d_out (dead before attn)
  float* part = (float*)((char*)d_ws + (32u << 20));   // [32,48) MB (mode 1)
  float* ml = (float*)((char*)d_ws + (48u << 20));     // 64 KB      (mode 1)

  const int mode = (ws_size >= (size_t)49 * 1048576) ? 1 : 0;

  conv_x<<<(SEQ * EMBED) / (256 * 16), 256, 0, stream>>>(x, xbf);
  conv_wT<<<dim3(NQKV / 64, EMBED / 64), 256, 0, stream>>>(W, wT);
  qkv_gemm<<<(SEQ / 128) * (NQKV / 128), 256, 0, stream>>>(xbf, wT, bias, qkv);
  v_transpose<<<dim3(SEQ / 64, EMBED / 64), 256, 0, stream>>>(qkv, vT);
  attn<<<SEQ / 16, 512, 0, stream>>>(qkv, vT, out, part, ml, mode);
  if (mode) attn_merge<<<SEQ / 16, 256, 0, stream>>>(ml, part, out);
}